// Round 4
// baseline (123.565 us; speedup 1.0000x reference)
//
#include <hip/hip_runtime.h>

#define K_DIM 4096
#define N_DIM 8192
#define CS_BLOCKS 256           // colsum blocks, 16 consecutive rows each
#define CS_ROWS (K_DIM / CS_BLOCKS)
#define RF_BLOCKS 256           // rowfused blocks, 16 rows each
#define RF_ROWS (K_DIM / RF_BLOCKS)

// ws float layout (plain stores only, no pre-zeroing):
// [0, 2M)            : partial0 (CS_BLOCKS x N column-sum partials of Hxs)   8 MB
// [2M, 4M)           : partial1 (RF_BLOCKS x N column-sum partials of Hxs_new) 8 MB
// then: prior_eps[N], dope[N], Tt[N], flag(int), nzp[CS_BLOCKS]

__device__ __forceinline__ float fast_tanh_half(float h) {
    // tanh(h/2) = 1 - 2/(e^h + 1)
    float e = __expf(h);
    float r = __builtin_amdgcn_rcpf(e + 1.0f);
    return __builtin_fmaf(-2.0f, r, 1.0f);
}

// out = clip(2*atanh(P/t), -1, 1) for t != 0, else 0.
// 2*atanh(P/t) = ln((t+P)/(t-P))
__device__ __forceinline__ float check_msg(float t, float P) {
    float num = t + P;
    float den = t - P;
    float q = num * __builtin_amdgcn_rcpf(den);
    float m = 0.69314718055994531f * __log2f(q);
    m = fminf(fmaxf(m, -1.0f), 1.0f);
    return (t == 0.0f) ? 0.0f : m;
}

// Sequential-streaming partial column sums of Hxs. grid=CS_BLOCKS, block=1024.
// Block b reads rows [b*16, b*16+16) fully sequentially; thread t owns cols
// 4t..4t+3 and 4096+4t..4096+4t+3 (register accumulators). Plain stores.
__global__ __launch_bounds__(1024) void colsum_seq_kernel(const float* __restrict__ M,
                                                          float* __restrict__ partial,
                                                          int* __restrict__ nzp) {
    const int t = threadIdx.x;
    const int b = blockIdx.x;
    const float4* p = reinterpret_cast<const float4*>(M + (size_t)b * CS_ROWS * N_DIM);
    float4 a0 = {0.f, 0.f, 0.f, 0.f};
    float4 a1 = {0.f, 0.f, 0.f, 0.f};
    unsigned int nzbits = 0u;
    #pragma unroll
    for (int r = 0; r < CS_ROWS; ++r) {
        float4 v0 = p[r * (N_DIM / 4) + t];
        float4 v1 = p[r * (N_DIM / 4) + t + 1024];
        a0.x += v0.x; a0.y += v0.y; a0.z += v0.z; a0.w += v0.w;
        a1.x += v1.x; a1.y += v1.y; a1.z += v1.z; a1.w += v1.w;
        uint4 u0 = *reinterpret_cast<const uint4*>(&v0);
        uint4 u1 = *reinterpret_cast<const uint4*>(&v1);
        nzbits |= (u0.x | u0.y | u0.z | u0.w | u1.x | u1.y | u1.z | u1.w);
    }
    float4* pr = reinterpret_cast<float4*>(partial + (size_t)b * N_DIM);
    pr[t] = a0;
    pr[t + 1024] = a1;

    __shared__ int snz;
    if (t == 0) snz = 0;
    __syncthreads();
    if (__any(nzbits != 0u ? 1 : 0)) {
        if ((t & 63) == 0) atomicOr(&snz, 1);     // LDS atomic only
    }
    __syncthreads();
    if (t == 0) nzp[b] = snz;                      // plain global store
}

// Fused reduce + per-column prep. grid = N/256 / ... = 32 blocks x 1024.
// Thread (q = t>>8, n = blk*256 + (t&255)) sums 64 partials; LDS combine.
// Block 0 also OR-reduces nzp[CS_BLOCKS] -> flag.
__global__ __launch_bounds__(1024) void prep_kernel(const float* __restrict__ ps,
                                                    const float* __restrict__ Min,
                                                    const float* __restrict__ partial,
                                                    const int* __restrict__ nzp,
                                                    float* __restrict__ prior_eps,
                                                    float* __restrict__ dope_out,
                                                    float* __restrict__ Tt,
                                                    int* __restrict__ flag) {
    const int t = threadIdx.x;
    const int lane = t & 255;
    const int q = t >> 8;                  // 0..3
    const int n = blockIdx.x * 256 + lane;

    float cs = 0.0f;
    #pragma unroll 8
    for (int i = 0; i < CS_BLOCKS / 4; ++i)
        cs += partial[(size_t)(q * (CS_BLOCKS / 4) + i) * N_DIM + n];

    __shared__ float red[4][256];
    __shared__ int rnz[4];
    if (blockIdx.x == 0 && t < 256) {
        int myany = __any(nzp[t] != 0 ? 1 : 0) ? 1 : 0;
        if ((t & 63) == 0) rnz[t >> 6] = myany;
    }
    red[q][lane] = cs;
    __syncthreads();

    if (blockIdx.x == 0 && t == 0)
        flag[0] = (rnz[0] | rnz[1] | rnz[2] | rnz[3]);

    if (q == 0) {
        cs = red[0][lane] + red[1][lane] + red[2][lane] + red[3][lane];

        const float INFCAP = 100.0f;
        const float EPSV = 1e-4f;

        float p0 = ps[2 * n], p1 = ps[2 * n + 1];
        float p1n = p1 / (p0 + p1);
        float dope = logf(1.0f - p1n) - logf(p1n);

        float m0 = Min[2 * n], m1 = Min[2 * n + 1];
        float m1n = m1 / (m0 + m1);
        float phi = logf(1.0f - m1n) - logf(m1n);

        float prior = dope + phi + cs;
        prior = fminf(fmaxf(prior, -INFCAP), INFCAP);
        float pe = prior + EPSV;

        prior_eps[n] = pe;
        dope_out[n] = dope;
        Tt[n] = tanhf(pe * 0.5f);
    }
}

// Fused check-node update + column-sum of the output.
// grid = RF_BLOCKS, block = 1024. Block handles 16 rows in 4 chunks of 4.
// Thread t owns cols 4t..4t+3 and 4096+4t..4096+4t+3 for every row.
__global__ __launch_bounds__(1024) void rowfused_kernel(const float* __restrict__ Hxs,
                                                        const int* __restrict__ H,
                                                        const int* __restrict__ x,
                                                        const float* __restrict__ prior_eps,
                                                        const float* __restrict__ Tt,
                                                        const int* __restrict__ flag,
                                                        float* __restrict__ out,
                                                        float* __restrict__ partial) {
    const int t = threadIdx.x;
    const int b = blockIdx.x;
    const int k0 = b * RF_ROWS;
    const int wid = t >> 6;
    const int lane = t & 63;

    const float4* T4 = reinterpret_cast<const float4*>(Tt);
    const float4* PE4 = reinterpret_cast<const float4*>(prior_eps);
    const bool fast = (*flag == 0);

    // Fixed-column per-thread data (registers for the whole block lifetime)
    float4 T0, T1, pe0, pe1;
    if (fast) { T0 = T4[t]; T1 = T4[t + 1024]; }
    else      { pe0 = PE4[t]; pe1 = PE4[t + 1024]; }

    float4 acc0 = {0.f, 0.f, 0.f, 0.f};
    float4 acc1 = {0.f, 0.f, 0.f, 0.f};

    __shared__ float wp[4][16];

    for (int c = 0; c < RF_ROWS / 4; ++c) {
        float tv[4][8];
        float lp[4] = {1.f, 1.f, 1.f, 1.f};

        #pragma unroll
        for (int j = 0; j < 4; ++j) {
            const int k = k0 + c * 4 + j;
            const int4* H4 = reinterpret_cast<const int4*>(H + (size_t)k * N_DIM);
            const int4 h0 = H4[t];
            const int4 h1 = H4[t + 1024];
            if (fast) {
                tv[j][0] = h0.x ? T0.x : 0.0f;
                tv[j][1] = h0.y ? T0.y : 0.0f;
                tv[j][2] = h0.z ? T0.z : 0.0f;
                tv[j][3] = h0.w ? T0.w : 0.0f;
                tv[j][4] = h1.x ? T1.x : 0.0f;
                tv[j][5] = h1.y ? T1.y : 0.0f;
                tv[j][6] = h1.z ? T1.z : 0.0f;
                tv[j][7] = h1.w ? T1.w : 0.0f;
            } else {
                const float4* HX4 = reinterpret_cast<const float4*>(Hxs + (size_t)k * N_DIM);
                const float4 hx0 = HX4[t];
                const float4 hx1 = HX4[t + 1024];
                tv[j][0] = fast_tanh_half((h0.x ? pe0.x : 0.0f) - hx0.x);
                tv[j][1] = fast_tanh_half((h0.y ? pe0.y : 0.0f) - hx0.y);
                tv[j][2] = fast_tanh_half((h0.z ? pe0.z : 0.0f) - hx0.z);
                tv[j][3] = fast_tanh_half((h0.w ? pe0.w : 0.0f) - hx0.w);
                tv[j][4] = fast_tanh_half((h1.x ? pe1.x : 0.0f) - hx1.x);
                tv[j][5] = fast_tanh_half((h1.y ? pe1.y : 0.0f) - hx1.y);
                tv[j][6] = fast_tanh_half((h1.z ? pe1.z : 0.0f) - hx1.z);
                tv[j][7] = fast_tanh_half((h1.w ? pe1.w : 0.0f) - hx1.w);
            }
            #pragma unroll
            for (int e = 0; e < 8; ++e) {
                float v = tv[j][e];
                lp[j] *= (v == 0.0f) ? 1.0f : v;
            }
        }

        // 4 block-wide products: wave butterfly, then 16-wave LDS combine.
        #pragma unroll
        for (int j = 0; j < 4; ++j) {
            #pragma unroll
            for (int off = 1; off < 64; off <<= 1)
                lp[j] *= __shfl_xor(lp[j], off);
        }
        if (lane == 0) {
            wp[0][wid] = lp[0];
            wp[1][wid] = lp[1];
            wp[2][wid] = lp[2];
            wp[3][wid] = lp[3];
        }
        __syncthreads();

        float P[4];
        #pragma unroll
        for (int j = 0; j < 4; ++j) {
            float pr = 1.0f;
            #pragma unroll
            for (int w = 0; w < 16; ++w) pr *= wp[j][w];
            const int k = k0 + c * 4 + j;
            const float sgn = 1.0f - 2.0f * (float)x[k];
            P[j] = sgn * pr;
        }
        __syncthreads();   // wp reused next chunk

        #pragma unroll
        for (int j = 0; j < 4; ++j) {
            const int k = k0 + c * 4 + j;
            float4 o0, o1;
            o0.x = check_msg(tv[j][0], P[j]);
            o0.y = check_msg(tv[j][1], P[j]);
            o0.z = check_msg(tv[j][2], P[j]);
            o0.w = check_msg(tv[j][3], P[j]);
            o1.x = check_msg(tv[j][4], P[j]);
            o1.y = check_msg(tv[j][5], P[j]);
            o1.z = check_msg(tv[j][6], P[j]);
            o1.w = check_msg(tv[j][7], P[j]);
            float4* orow = reinterpret_cast<float4*>(out + (size_t)k * N_DIM);
            orow[t] = o0;
            orow[t + 1024] = o1;
            acc0.x += o0.x; acc0.y += o0.y; acc0.z += o0.z; acc0.w += o0.w;
            acc1.x += o1.x; acc1.y += o1.y; acc1.z += o1.z; acc1.w += o1.w;
        }
    }

    float4* pr = reinterpret_cast<float4*>(partial + (size_t)b * N_DIM);
    pr[t] = acc0;
    pr[t + 1024] = acc1;
}

// Fused reduce + output beliefs. grid = 32 blocks x 1024 (same split as prep).
__global__ __launch_bounds__(1024) void final_kernel(const float* __restrict__ partial,
                                                     const float* __restrict__ dope,
                                                     float* __restrict__ Mout) {
    const int t = threadIdx.x;
    const int lane = t & 255;
    const int q = t >> 8;
    const int n = blockIdx.x * 256 + lane;

    float cs = 0.0f;
    #pragma unroll 8
    for (int i = 0; i < RF_BLOCKS / 4; ++i)
        cs += partial[(size_t)(q * (RF_BLOCKS / 4) + i) * N_DIM + n];

    __shared__ float red[4][256];
    red[q][lane] = cs;
    __syncthreads();

    if (q == 0) {
        cs = red[0][lane] + red[1][lane] + red[2][lane] + red[3][lane];
        float z = (1.0f - tanhf((cs + dope[n]) * 0.5f)) * 0.5f;
        float2 m; m.x = 1.0f - z; m.y = z;
        reinterpret_cast<float2*>(Mout)[n] = m;
    }
}

extern "C" void kernel_launch(void* const* d_in, const int* in_sizes, int n_in,
                              void* d_out, int out_size, void* d_ws, size_t ws_size,
                              hipStream_t stream) {
    (void)in_sizes; (void)n_in; (void)out_size; (void)ws_size;
    const float* ps  = (const float*)d_in[0];
    const float* Min = (const float*)d_in[1];
    const float* Hxs = (const float*)d_in[2];
    const int*   x   = (const int*)d_in[3];
    const int*   H   = (const int*)d_in[4];

    float* out = (float*)d_out;
    float* Mout = out;                       // N*2 floats
    float* Hxs_new = out + 2 * N_DIM;        // K*N floats

    float* ws = (float*)d_ws;
    float* partial0   = ws;                                       // CS_BLOCKS*N (8 MB)
    float* partial1   = ws + (size_t)CS_BLOCKS * N_DIM;           // RF_BLOCKS*N (8 MB)
    float* prior_eps  = partial1 + (size_t)RF_BLOCKS * N_DIM;
    float* dope       = prior_eps + N_DIM;
    float* Tt         = dope + N_DIM;
    int*   flag       = (int*)(Tt + N_DIM);
    int*   nzp        = flag + 64;                                // CS_BLOCKS ints

    colsum_seq_kernel<<<CS_BLOCKS, 1024, 0, stream>>>(Hxs, partial0, nzp);

    prep_kernel<<<N_DIM / 256, 1024, 0, stream>>>(ps, Min, partial0, nzp,
                                                  prior_eps, dope, Tt, flag);

    rowfused_kernel<<<RF_BLOCKS, 1024, 0, stream>>>(Hxs, H, x, prior_eps, Tt, flag,
                                                    Hxs_new, partial1);

    final_kernel<<<N_DIM / 256, 1024, 0, stream>>>(partial1, dope, Mout);
}

// Round 5
// 112.025 us; speedup vs baseline: 1.1030x; 1.1030x over previous
//
#include <hip/hip_runtime.h>

#define K_DIM 4096
#define N_DIM 8192
#define CS_RBLK 64              // colsum row-blocks (64 rows each)
#define CS_CBLK 8               // colsum col-blocks (1024 cols each)
#define RF_BLOCKS 512           // rowfused blocks
#define RF_ROWS 8               // rows per rowfused block (2 chunks of 4)

// ws float layout (plain stores only, no pre-zeroing; regions aliased by time):
// [0, RF_BLOCKS*N)   : partial1 (rowfused column-sum partials, 16 MB)
//                      partial0 (colsum partials, 2 MB) ALIASES the start of
//                      this region: written by dispatch 1, consumed by
//                      dispatch 2, dead before dispatch 3 writes partial1.
// then: prior_eps[N], dope[N], Tt[N], flag(int), nzp[512]

__device__ __forceinline__ float fast_tanh_half(float h) {
    // tanh(h/2) = 1 - 2/(e^h + 1)
    float e = __expf(h);
    float r = __builtin_amdgcn_rcpf(e + 1.0f);
    return __builtin_fmaf(-2.0f, r, 1.0f);
}

// out = clip(2*atanh(P/t), -1, 1) for t != 0, else 0.
// 2*atanh(P/t) = ln((t+P)/(t-P))
__device__ __forceinline__ float check_msg(float t, float P) {
    float num = t + P;
    float den = t - P;
    float q = num * __builtin_amdgcn_rcpf(den);
    float m = 0.69314718055994531f * __log2f(q);
    m = fminf(fmaxf(m, -1.0f), 1.0f);
    return (t == 0.0f) ? 0.0f : m;
}

// Partial column sums over [K,N] f32. grid=(CS_CBLK, CS_RBLK), block=256.
// Each thread: 4 consecutive cols x 64 rows. Plain stores.
__global__ __launch_bounds__(256) void colsum_part_kernel(const float* __restrict__ M,
                                                          float* __restrict__ partial,
                                                          int* __restrict__ nzp) {
    const int c0 = blockIdx.x * 1024 + threadIdx.x * 4;
    const int r0 = blockIdx.y * (K_DIM / CS_RBLK);
    const float4* p = reinterpret_cast<const float4*>(M + (size_t)r0 * N_DIM + c0);
    float sx = 0.f, sy = 0.f, sz = 0.f, sw = 0.f;
    unsigned int nzbits = 0u;
    #pragma unroll 8
    for (int r = 0; r < K_DIM / CS_RBLK; ++r) {
        float4 v = p[(size_t)r * (N_DIM / 4)];
        sx += v.x; sy += v.y; sz += v.z; sw += v.w;
        uint4 u = *reinterpret_cast<const uint4*>(&v);
        nzbits |= (u.x | u.y | u.z | u.w);   // false-positive on -0.0 only -> safe general path
    }
    float4 s; s.x = sx; s.y = sy; s.z = sz; s.w = sw;
    reinterpret_cast<float4*>(partial + (size_t)blockIdx.y * N_DIM)[c0 / 4] = s;

    __shared__ int snz;
    if (threadIdx.x == 0) snz = 0;
    __syncthreads();
    if (__any(nzbits != 0u ? 1 : 0)) {
        if ((threadIdx.x & 63) == 0) atomicOr(&snz, 1);   // LDS atomic only
    }
    __syncthreads();
    if (threadIdx.x == 0)
        nzp[blockIdx.y * gridDim.x + blockIdx.x] = snz;    // plain global store
}

// Fused reduce + per-column prep. grid = N/256 = 32 blocks, block = 256.
// Block 0 also OR-reduces nzp[512] -> flag (plain store).
__global__ __launch_bounds__(256) void prep_kernel(const float* __restrict__ ps,
                                                   const float* __restrict__ Min,
                                                   const float* __restrict__ partial,
                                                   const int* __restrict__ nzp,
                                                   float* __restrict__ prior_eps,
                                                   float* __restrict__ dope_out,
                                                   float* __restrict__ Tt,
                                                   int* __restrict__ flag) {
    const int n = blockIdx.x * 256 + threadIdx.x;
    float cs = 0.0f;
    #pragma unroll 8
    for (int r = 0; r < CS_RBLK; ++r) cs += partial[(size_t)r * N_DIM + n];

    const float INFCAP = 100.0f;
    const float EPSV = 1e-4f;

    float p0 = ps[2 * n], p1 = ps[2 * n + 1];
    float p1n = p1 / (p0 + p1);
    float dope = logf(1.0f - p1n) - logf(p1n);

    float m0 = Min[2 * n], m1 = Min[2 * n + 1];
    float m1n = m1 / (m0 + m1);
    float phi = logf(1.0f - m1n) - logf(m1n);

    float prior = dope + phi + cs;
    prior = fminf(fmaxf(prior, -INFCAP), INFCAP);
    float pe = prior + EPSV;

    prior_eps[n] = pe;
    dope_out[n] = dope;
    Tt[n] = tanhf(pe * 0.5f);

    if (blockIdx.x == 0) {
        int v = nzp[threadIdx.x] | nzp[threadIdx.x + 256];   // 512 entries
        int any = __any(v ? 1 : 0) ? 1 : 0;
        __shared__ int w[4];
        if ((threadIdx.x & 63) == 0) w[threadIdx.x >> 6] = any;
        __syncthreads();
        if (threadIdx.x == 0) flag[0] = (w[0] | w[1] | w[2] | w[3]);
    }
}

// Fused check-node update + column-sum of the output.
// grid = RF_BLOCKS (512) x 1024 threads -> 2 blocks/CU co-resident.
// Block handles RF_ROWS=8 rows in 2 chunks of 4; ONE barrier per chunk
// (double-buffered wp). Thread t owns cols 4t..4t+3 and 4096+4t..4096+4t+3.
__global__ __launch_bounds__(1024) void rowfused_kernel(const float* __restrict__ Hxs,
                                                        const int* __restrict__ H,
                                                        const int* __restrict__ x,
                                                        const float* __restrict__ prior_eps,
                                                        const float* __restrict__ Tt,
                                                        const int* __restrict__ flag,
                                                        float* __restrict__ out,
                                                        float* __restrict__ partial) {
    const int t = threadIdx.x;
    const int b = blockIdx.x;
    const int k0 = b * RF_ROWS;
    const int wid = t >> 6;
    const int lane = t & 63;

    const float4* T4 = reinterpret_cast<const float4*>(Tt);
    const float4* PE4 = reinterpret_cast<const float4*>(prior_eps);
    const bool fast = (*flag == 0);

    // Fixed-column per-thread data (registers for the whole block lifetime)
    float4 T0, T1, pe0, pe1;
    if (fast) { T0 = T4[t]; T1 = T4[t + 1024]; }
    else      { pe0 = PE4[t]; pe1 = PE4[t + 1024]; }

    float4 acc0 = {0.f, 0.f, 0.f, 0.f};
    float4 acc1 = {0.f, 0.f, 0.f, 0.f};

    __shared__ float wp[2][4][16];

    for (int c = 0; c < RF_ROWS / 4; ++c) {
        const int p = c & 1;
        float tv[4][8];
        float lp[4] = {1.f, 1.f, 1.f, 1.f};

        #pragma unroll
        for (int j = 0; j < 4; ++j) {
            const int k = k0 + c * 4 + j;
            const int4* H4 = reinterpret_cast<const int4*>(H + (size_t)k * N_DIM);
            const int4 h0 = H4[t];
            const int4 h1 = H4[t + 1024];
            if (fast) {
                tv[j][0] = h0.x ? T0.x : 0.0f;
                tv[j][1] = h0.y ? T0.y : 0.0f;
                tv[j][2] = h0.z ? T0.z : 0.0f;
                tv[j][3] = h0.w ? T0.w : 0.0f;
                tv[j][4] = h1.x ? T1.x : 0.0f;
                tv[j][5] = h1.y ? T1.y : 0.0f;
                tv[j][6] = h1.z ? T1.z : 0.0f;
                tv[j][7] = h1.w ? T1.w : 0.0f;
            } else {
                const float4* HX4 = reinterpret_cast<const float4*>(Hxs + (size_t)k * N_DIM);
                const float4 hx0 = HX4[t];
                const float4 hx1 = HX4[t + 1024];
                tv[j][0] = fast_tanh_half((h0.x ? pe0.x : 0.0f) - hx0.x);
                tv[j][1] = fast_tanh_half((h0.y ? pe0.y : 0.0f) - hx0.y);
                tv[j][2] = fast_tanh_half((h0.z ? pe0.z : 0.0f) - hx0.z);
                tv[j][3] = fast_tanh_half((h0.w ? pe0.w : 0.0f) - hx0.w);
                tv[j][4] = fast_tanh_half((h1.x ? pe1.x : 0.0f) - hx1.x);
                tv[j][5] = fast_tanh_half((h1.y ? pe1.y : 0.0f) - hx1.y);
                tv[j][6] = fast_tanh_half((h1.z ? pe1.z : 0.0f) - hx1.z);
                tv[j][7] = fast_tanh_half((h1.w ? pe1.w : 0.0f) - hx1.w);
            }
            #pragma unroll
            for (int e = 0; e < 8; ++e) {
                float v = tv[j][e];
                lp[j] *= (v == 0.0f) ? 1.0f : v;
            }
        }

        // 4 block-wide products: wave butterfly, then 16-wave LDS combine.
        #pragma unroll
        for (int j = 0; j < 4; ++j) {
            #pragma unroll
            for (int off = 1; off < 64; off <<= 1)
                lp[j] *= __shfl_xor(lp[j], off);
        }
        if (lane == 0) {
            wp[p][0][wid] = lp[0];
            wp[p][1][wid] = lp[1];
            wp[p][2][wid] = lp[2];
            wp[p][3][wid] = lp[3];
        }
        __syncthreads();      // the ONLY barrier in the chunk

        float P[4];
        #pragma unroll
        for (int j = 0; j < 4; ++j) {
            float pr = 1.0f;
            #pragma unroll
            for (int w = 0; w < 16; ++w) pr *= wp[p][j][w];
            const int k = k0 + c * 4 + j;
            const float sgn = 1.0f - 2.0f * (float)x[k];
            P[j] = sgn * pr;
        }

        #pragma unroll
        for (int j = 0; j < 4; ++j) {
            const int k = k0 + c * 4 + j;
            float4 o0, o1;
            o0.x = check_msg(tv[j][0], P[j]);
            o0.y = check_msg(tv[j][1], P[j]);
            o0.z = check_msg(tv[j][2], P[j]);
            o0.w = check_msg(tv[j][3], P[j]);
            o1.x = check_msg(tv[j][4], P[j]);
            o1.y = check_msg(tv[j][5], P[j]);
            o1.z = check_msg(tv[j][6], P[j]);
            o1.w = check_msg(tv[j][7], P[j]);
            float4* orow = reinterpret_cast<float4*>(out + (size_t)k * N_DIM);
            orow[t] = o0;
            orow[t + 1024] = o1;
            acc0.x += o0.x; acc0.y += o0.y; acc0.z += o0.z; acc0.w += o0.w;
            acc1.x += o1.x; acc1.y += o1.y; acc1.z += o1.z; acc1.w += o1.w;
        }
    }

    float4* pr = reinterpret_cast<float4*>(partial + (size_t)b * N_DIM);
    pr[t] = acc0;
    pr[t + 1024] = acc1;
}

// Fused reduce + output beliefs. grid = 32 blocks x 1024, 4-way column split.
__global__ __launch_bounds__(1024) void final_kernel(const float* __restrict__ partial,
                                                     const float* __restrict__ dope,
                                                     float* __restrict__ Mout) {
    const int t = threadIdx.x;
    const int lane = t & 255;
    const int q = t >> 8;
    const int n = blockIdx.x * 256 + lane;

    float cs = 0.0f;
    #pragma unroll 8
    for (int i = 0; i < RF_BLOCKS / 4; ++i)
        cs += partial[(size_t)(q * (RF_BLOCKS / 4) + i) * N_DIM + n];

    __shared__ float red[4][256];
    red[q][lane] = cs;
    __syncthreads();

    if (q == 0) {
        cs = red[0][lane] + red[1][lane] + red[2][lane] + red[3][lane];
        float z = (1.0f - tanhf((cs + dope[n]) * 0.5f)) * 0.5f;
        float2 m; m.x = 1.0f - z; m.y = z;
        reinterpret_cast<float2*>(Mout)[n] = m;
    }
}

extern "C" void kernel_launch(void* const* d_in, const int* in_sizes, int n_in,
                              void* d_out, int out_size, void* d_ws, size_t ws_size,
                              hipStream_t stream) {
    (void)in_sizes; (void)n_in; (void)out_size; (void)ws_size;
    const float* ps  = (const float*)d_in[0];
    const float* Min = (const float*)d_in[1];
    const float* Hxs = (const float*)d_in[2];
    const int*   x   = (const int*)d_in[3];
    const int*   H   = (const int*)d_in[4];

    float* out = (float*)d_out;
    float* Mout = out;                       // N*2 floats
    float* Hxs_new = out + 2 * N_DIM;        // K*N floats

    float* ws = (float*)d_ws;
    float* partial1   = ws;                                  // RF_BLOCKS*N (16 MB)
    float* partial0   = ws;                                  // CS_RBLK*N (2 MB) -- aliased by time
    float* prior_eps  = ws + (size_t)RF_BLOCKS * N_DIM;
    float* dope       = prior_eps + N_DIM;
    float* Tt         = dope + N_DIM;
    int*   flag       = (int*)(Tt + N_DIM);
    int*   nzp        = flag + 64;                           // 512 ints

    dim3 csgrid(CS_CBLK, CS_RBLK);
    colsum_part_kernel<<<csgrid, 256, 0, stream>>>(Hxs, partial0, nzp);

    prep_kernel<<<N_DIM / 256, 256, 0, stream>>>(ps, Min, partial0, nzp,
                                                 prior_eps, dope, Tt, flag);

    rowfused_kernel<<<RF_BLOCKS, 1024, 0, stream>>>(Hxs, H, x, prior_eps, Tt, flag,
                                                    Hxs_new, partial1);

    final_kernel<<<N_DIM / 256, 1024, 0, stream>>>(partial1, dope, Mout);
}

// Round 6
// 105.456 us; speedup vs baseline: 1.1717x; 1.0623x over previous
//
#include <hip/hip_runtime.h>

#define K_DIM 4096
#define N_DIM 8192
#define CS_RBLK 64              // colsum row-blocks (64 rows each)
#define CS_CBLK 8               // colsum col-blocks (1024 cols each)
#define MAIN_BLOCKS 512         // main kernel blocks (2 per CU)
#define MAIN_ROWS 8             // rows per block, 2 waves per row (16 waves)

// ws float layout (plain stores only, no pre-zeroing; regions aliased by time):
// [0, MAIN_BLOCKS*N)  : partial1 (main column-sum partials, 16 MB)
//                       partial0 (colsum partials, 2 MB) ALIASES the start:
//                       written by dispatch 1, consumed by dispatch 2, dead
//                       before dispatch 3 writes partial1.
// then: prior_eps[N], dope[N], Tt[N], flag(int), nzp[512]

__device__ __forceinline__ float fast_tanh_half(float h) {
    // tanh(h/2) = 1 - 2/(e^h + 1)
    float e = __expf(h);
    float r = __builtin_amdgcn_rcpf(e + 1.0f);
    return __builtin_fmaf(-2.0f, r, 1.0f);
}

// out = clip(2*atanh(P/t), -1, 1) for t != 0, else 0.
// 2*atanh(P/t) = ln((t+P)/(t-P))
__device__ __forceinline__ float check_msg(float t, float P) {
    float num = t + P;
    float den = t - P;
    float q = num * __builtin_amdgcn_rcpf(den);
    float m = 0.69314718055994531f * __log2f(q);
    m = fminf(fmaxf(m, -1.0f), 1.0f);
    return (t == 0.0f) ? 0.0f : m;
}

// Partial column sums over [K,N] f32. grid=(CS_CBLK, CS_RBLK), block=256.
// Each thread: 4 consecutive cols x 64 rows. Plain stores.
__global__ __launch_bounds__(256) void colsum_part_kernel(const float* __restrict__ M,
                                                          float* __restrict__ partial,
                                                          int* __restrict__ nzp) {
    const int c0 = blockIdx.x * 1024 + threadIdx.x * 4;
    const int r0 = blockIdx.y * (K_DIM / CS_RBLK);
    const float4* p = reinterpret_cast<const float4*>(M + (size_t)r0 * N_DIM + c0);
    float sx = 0.f, sy = 0.f, sz = 0.f, sw = 0.f;
    unsigned int nzbits = 0u;
    #pragma unroll 8
    for (int r = 0; r < K_DIM / CS_RBLK; ++r) {
        float4 v = p[(size_t)r * (N_DIM / 4)];
        sx += v.x; sy += v.y; sz += v.z; sw += v.w;
        uint4 u = *reinterpret_cast<const uint4*>(&v);
        nzbits |= (u.x | u.y | u.z | u.w);   // false-positive on -0.0 only -> safe general path
    }
    float4 s; s.x = sx; s.y = sy; s.z = sz; s.w = sw;
    reinterpret_cast<float4*>(partial + (size_t)blockIdx.y * N_DIM)[c0 / 4] = s;

    __shared__ int snz;
    if (threadIdx.x == 0) snz = 0;
    __syncthreads();
    if (__any(nzbits != 0u ? 1 : 0)) {
        if ((threadIdx.x & 63) == 0) atomicOr(&snz, 1);   // LDS atomic only
    }
    __syncthreads();
    if (threadIdx.x == 0)
        nzp[blockIdx.y * gridDim.x + blockIdx.x] = snz;    // plain global store
}

// Fused reduce + per-column prep. grid = N/256 = 32 blocks, block = 256.
// Block 0 also OR-reduces nzp[512] -> flag (plain store).
__global__ __launch_bounds__(256) void prep_kernel(const float* __restrict__ ps,
                                                   const float* __restrict__ Min,
                                                   const float* __restrict__ partial,
                                                   const int* __restrict__ nzp,
                                                   float* __restrict__ prior_eps,
                                                   float* __restrict__ dope_out,
                                                   float* __restrict__ Tt,
                                                   int* __restrict__ flag) {
    const int n = blockIdx.x * 256 + threadIdx.x;
    float cs = 0.0f;
    #pragma unroll 8
    for (int r = 0; r < CS_RBLK; ++r) cs += partial[(size_t)r * N_DIM + n];

    const float INFCAP = 100.0f;
    const float EPSV = 1e-4f;

    float p0 = ps[2 * n], p1 = ps[2 * n + 1];
    float p1n = p1 / (p0 + p1);
    float dope = logf(1.0f - p1n) - logf(p1n);

    float m0 = Min[2 * n], m1 = Min[2 * n + 1];
    float m1n = m1 / (m0 + m1);
    float phi = logf(1.0f - m1n) - logf(m1n);

    float prior = dope + phi + cs;
    prior = fminf(fmaxf(prior, -INFCAP), INFCAP);
    float pe = prior + EPSV;

    prior_eps[n] = pe;
    dope_out[n] = dope;
    Tt[n] = tanhf(pe * 0.5f);

    if (blockIdx.x == 0) {
        int v = nzp[threadIdx.x] | nzp[threadIdx.x + 256];   // 512 entries
        int any = __any(v ? 1 : 0) ? 1 : 0;
        __shared__ int w[4];
        if ((threadIdx.x & 63) == 0) w[threadIdx.x >> 6] = any;
        __syncthreads();
        if (threadIdx.x == 0) flag[0] = (w[0] | w[1] | w[2] | w[3]);
    }
}

// Main check-node update + column-sum partials.
// grid = MAIN_BLOCKS (512) x 1024 thr -> 2 blocks/CU, 32 waves/CU.
// 8 rows per block, TWO waves per row (each wave = half a row, 16 int4/lane).
// Phase 1: per-wave half-row product (no sync). ONE barrier.
// Phase 2: P per row; if product underflowed to zero (the overwhelmingly
// common case for ~2048-factor |tanh|<1 products) -> stream zeros, no loads;
// else recompute t (L2-hot) + check_msg + LDS colsum accumulation.
__global__ __launch_bounds__(1024) void main_kernel(const float* __restrict__ Hxs,
                                                    const int* __restrict__ H,
                                                    const int* __restrict__ x,
                                                    const float* __restrict__ prior_eps,
                                                    const float* __restrict__ Tt,
                                                    const int* __restrict__ flag,
                                                    float* __restrict__ out,
                                                    float* __restrict__ partial) {
    const int t = threadIdx.x;
    const int wid = t >> 6;         // 0..15
    const int lane = t & 63;
    const int r = wid >> 1;         // row slot 0..7
    const int half = wid & 1;       // which half of the row
    const int b = blockIdx.x;
    const int k = b * MAIN_ROWS + r;

    __shared__ float csum[N_DIM];   // 32 KB block-level column-sum accumulator
    __shared__ float wpair[MAIN_ROWS][2];

    // init LDS colsum (zero)
    float4* cs4 = reinterpret_cast<float4*>(csum);
    {
        float4 z = {0.f, 0.f, 0.f, 0.f};
        cs4[t] = z;
        cs4[t + 1024] = z;
    }

    const bool fast = (*flag == 0);

    const int4*   H4  = reinterpret_cast<const int4*>(H + (size_t)k * N_DIM);
    const float4* T4  = reinterpret_cast<const float4*>(Tt);
    const float4* PE4 = reinterpret_cast<const float4*>(prior_eps);
    const float4* HX4 = reinterpret_cast<const float4*>(Hxs + (size_t)k * N_DIM);

    const int base = half * 16 * 64 + lane;   // int4 index of first element

    // ---- phase 1: half-row product ----
    float lp0 = 1.f, lp1 = 1.f, lp2 = 1.f, lp3 = 1.f;
    if (fast) {
        #pragma unroll
        for (int s = 0; s < 16; s += 4) {
            #pragma unroll
            for (int u = 0; u < 4; ++u) {
                const int idx = base + (s + u) * 64;
                const int4 hh = H4[idx];
                const float4 tv = T4[idx];
                float f0 = (hh.x && tv.x != 0.f) ? tv.x : 1.f;
                float f1 = (hh.y && tv.y != 0.f) ? tv.y : 1.f;
                float f2 = (hh.z && tv.z != 0.f) ? tv.z : 1.f;
                float f3 = (hh.w && tv.w != 0.f) ? tv.w : 1.f;
                if (u == 0) lp0 *= f0 * f1 * f2 * f3;
                if (u == 1) lp1 *= f0 * f1 * f2 * f3;
                if (u == 2) lp2 *= f0 * f1 * f2 * f3;
                if (u == 3) lp3 *= f0 * f1 * f2 * f3;
            }
        }
    } else {
        #pragma unroll
        for (int s = 0; s < 16; s += 4) {
            #pragma unroll
            for (int u = 0; u < 4; ++u) {
                const int idx = base + (s + u) * 64;
                const int4 hh = H4[idx];
                const float4 pe = PE4[idx];
                const float4 hx = HX4[idx];
                float t0 = fast_tanh_half((hh.x ? pe.x : 0.f) - hx.x);
                float t1 = fast_tanh_half((hh.y ? pe.y : 0.f) - hx.y);
                float t2 = fast_tanh_half((hh.z ? pe.z : 0.f) - hx.z);
                float t3 = fast_tanh_half((hh.w ? pe.w : 0.f) - hx.w);
                t0 = (t0 == 0.f) ? 1.f : t0;
                t1 = (t1 == 0.f) ? 1.f : t1;
                t2 = (t2 == 0.f) ? 1.f : t2;
                t3 = (t3 == 0.f) ? 1.f : t3;
                if (u == 0) lp0 *= t0 * t1 * t2 * t3;
                if (u == 1) lp1 *= t0 * t1 * t2 * t3;
                if (u == 2) lp2 *= t0 * t1 * t2 * t3;
                if (u == 3) lp3 *= t0 * t1 * t2 * t3;
            }
        }
    }
    float lp = (lp0 * lp1) * (lp2 * lp3);
    #pragma unroll
    for (int off = 1; off < 64; off <<= 1)
        lp *= __shfl_xor(lp, off);
    if (lane == 0) wpair[r][half] = lp;

    __syncthreads();   // the ONLY mid-kernel barrier

    const float sgn = 1.0f - 2.0f * (float)x[k];
    const float P = sgn * (wpair[r][0] * wpair[r][1]);

    // ---- phase 2: outputs ----
    float4* orow = reinterpret_cast<float4*>(out + (size_t)k * N_DIM);
    if (fast && P == 0.0f) {
        // Exact-zero product: every output element is exactly 0 (t==0 -> 0;
        // t!=0 -> ln((t+0)/(t-0)) = 0). Pure write stream, no loads.
        const float4 z = {0.f, 0.f, 0.f, 0.f};
        #pragma unroll
        for (int s = 0; s < 16; ++s)
            orow[base + s * 64] = z;
    } else {
        #pragma unroll 4
        for (int s = 0; s < 16; ++s) {
            const int idx = base + s * 64;
            const int4 hh = H4[idx];   // L2-hot (read in phase 1)
            float t0, t1, t2, t3;
            if (fast) {
                const float4 tv = T4[idx];
                t0 = (hh.x && tv.x != 0.f) ? tv.x : 0.f;
                t1 = (hh.y && tv.y != 0.f) ? tv.y : 0.f;
                t2 = (hh.z && tv.z != 0.f) ? tv.z : 0.f;
                t3 = (hh.w && tv.w != 0.f) ? tv.w : 0.f;
            } else {
                const float4 pe = PE4[idx];
                const float4 hx = HX4[idx];
                t0 = fast_tanh_half((hh.x ? pe.x : 0.f) - hx.x);
                t1 = fast_tanh_half((hh.y ? pe.y : 0.f) - hx.y);
                t2 = fast_tanh_half((hh.z ? pe.z : 0.f) - hx.z);
                t3 = fast_tanh_half((hh.w ? pe.w : 0.f) - hx.w);
            }
            float4 o;
            o.x = check_msg(t0, P);
            o.y = check_msg(t1, P);
            o.z = check_msg(t2, P);
            o.w = check_msg(t3, P);
            orow[idx] = o;
            const int n0 = idx * 4;
            atomicAdd(&csum[n0 + 0], o.x);
            atomicAdd(&csum[n0 + 1], o.y);
            atomicAdd(&csum[n0 + 2], o.z);
            atomicAdd(&csum[n0 + 3], o.w);
        }
    }

    __syncthreads();
    float4* pr = reinterpret_cast<float4*>(partial + (size_t)b * N_DIM);
    pr[t] = cs4[t];
    pr[t + 1024] = cs4[t + 1024];
}

// Fused reduce + output beliefs. grid = 32 blocks x 1024, 4-way column split.
__global__ __launch_bounds__(1024) void final_kernel(const float* __restrict__ partial,
                                                     const float* __restrict__ dope,
                                                     float* __restrict__ Mout) {
    const int t = threadIdx.x;
    const int lane = t & 255;
    const int q = t >> 8;
    const int n = blockIdx.x * 256 + lane;

    float cs = 0.0f;
    #pragma unroll 8
    for (int i = 0; i < MAIN_BLOCKS / 4; ++i)
        cs += partial[(size_t)(q * (MAIN_BLOCKS / 4) + i) * N_DIM + n];

    __shared__ float red[4][256];
    red[q][lane] = cs;
    __syncthreads();

    if (q == 0) {
        cs = red[0][lane] + red[1][lane] + red[2][lane] + red[3][lane];
        float z = (1.0f - tanhf((cs + dope[n]) * 0.5f)) * 0.5f;
        float2 m; m.x = 1.0f - z; m.y = z;
        reinterpret_cast<float2*>(Mout)[n] = m;
    }
}

extern "C" void kernel_launch(void* const* d_in, const int* in_sizes, int n_in,
                              void* d_out, int out_size, void* d_ws, size_t ws_size,
                              hipStream_t stream) {
    (void)in_sizes; (void)n_in; (void)out_size; (void)ws_size;
    const float* ps  = (const float*)d_in[0];
    const float* Min = (const float*)d_in[1];
    const float* Hxs = (const float*)d_in[2];
    const int*   x   = (const int*)d_in[3];
    const int*   H   = (const int*)d_in[4];

    float* out = (float*)d_out;
    float* Mout = out;                       // N*2 floats
    float* Hxs_new = out + 2 * N_DIM;        // K*N floats

    float* ws = (float*)d_ws;
    float* partial1   = ws;                                  // MAIN_BLOCKS*N (16 MB)
    float* partial0   = ws;                                  // CS_RBLK*N (2 MB) -- aliased by time
    float* prior_eps  = ws + (size_t)MAIN_BLOCKS * N_DIM;
    float* dope       = prior_eps + N_DIM;
    float* Tt         = dope + N_DIM;
    int*   flag       = (int*)(Tt + N_DIM);
    int*   nzp        = flag + 64;                           // 512 ints

    dim3 csgrid(CS_CBLK, CS_RBLK);
    colsum_part_kernel<<<csgrid, 256, 0, stream>>>(Hxs, partial0, nzp);

    prep_kernel<<<N_DIM / 256, 256, 0, stream>>>(ps, Min, partial0, nzp,
                                                 prior_eps, dope, Tt, flag);

    main_kernel<<<MAIN_BLOCKS, 1024, 0, stream>>>(Hxs, H, x, prior_eps, Tt, flag,
                                                  Hxs_new, partial1);

    final_kernel<<<N_DIM / 256, 1024, 0, stream>>>(partial1, dope, Mout);
}

// Round 7
// 94.073 us; speedup vs baseline: 1.3135x; 1.1210x over previous
//
#include <hip/hip_runtime.h>

#define K_DIM 4096
#define N_DIM 8192
#define CS_RBLK 64              // colsum row-blocks (64 rows each)
#define CS_CBLK 8               // colsum col-blocks (1024 cols each)

// ws float layout (plain stores only, no pre-zeroing needed):
// [0, CS_RBLK*N)  : partial0 (colsum partials, 2 MB)
// then: prior_eps[N], dope[N], Tt[N], colsum_new[N], flag(int), nzp[512]

__device__ __forceinline__ float fast_tanh_half(float h) {
    // tanh(h/2) = 1 - 2/(e^h + 1)
    float e = __expf(h);
    float r = __builtin_amdgcn_rcpf(e + 1.0f);
    return __builtin_fmaf(-2.0f, r, 1.0f);
}

// out = clip(2*atanh(P/t), -1, 1) for t != 0, else 0.
// 2*atanh(P/t) = ln((t+P)/(t-P))
__device__ __forceinline__ float check_msg(float t, float P) {
    float num = t + P;
    float den = t - P;
    float q = num * __builtin_amdgcn_rcpf(den);
    float m = 0.69314718055994531f * __log2f(q);
    m = fminf(fmaxf(m, -1.0f), 1.0f);
    return (t == 0.0f) ? 0.0f : m;
}

// Partial column sums over [K,N] f32. grid=(CS_CBLK, CS_RBLK), block=256.
// Each thread: 4 consecutive cols x 64 rows. Plain stores.
__global__ __launch_bounds__(256) void colsum_part_kernel(const float* __restrict__ M,
                                                          float* __restrict__ partial,
                                                          int* __restrict__ nzp) {
    const int c0 = blockIdx.x * 1024 + threadIdx.x * 4;
    const int r0 = blockIdx.y * (K_DIM / CS_RBLK);
    const float4* p = reinterpret_cast<const float4*>(M + (size_t)r0 * N_DIM + c0);
    float sx = 0.f, sy = 0.f, sz = 0.f, sw = 0.f;
    unsigned int nzbits = 0u;
    #pragma unroll 8
    for (int r = 0; r < K_DIM / CS_RBLK; ++r) {
        float4 v = p[(size_t)r * (N_DIM / 4)];
        sx += v.x; sy += v.y; sz += v.z; sw += v.w;
        uint4 u = *reinterpret_cast<const uint4*>(&v);
        nzbits |= (u.x | u.y | u.z | u.w);   // false-positive on -0.0 only -> safe general path
    }
    float4 s; s.x = sx; s.y = sy; s.z = sz; s.w = sw;
    reinterpret_cast<float4*>(partial + (size_t)blockIdx.y * N_DIM)[c0 / 4] = s;

    __shared__ int snz;
    if (threadIdx.x == 0) snz = 0;
    __syncthreads();
    if (__any(nzbits != 0u ? 1 : 0)) {
        if ((threadIdx.x & 63) == 0) atomicOr(&snz, 1);   // LDS atomic only
    }
    __syncthreads();
    if (threadIdx.x == 0)
        nzp[blockIdx.y * gridDim.x + blockIdx.x] = snz;    // plain global store
}

// Fused reduce + per-column prep. grid = 128 blocks x 256 (4-way split per column).
// Also zeros colsum_new (one writer per element) and reduces nzp -> flag (block 0).
__global__ __launch_bounds__(256) void prep_kernel(const float* __restrict__ ps,
                                                   const float* __restrict__ Min,
                                                   const float* __restrict__ partial,
                                                   const int* __restrict__ nzp,
                                                   float* __restrict__ prior_eps,
                                                   float* __restrict__ dope_out,
                                                   float* __restrict__ Tt,
                                                   float* __restrict__ colsum_new,
                                                   int* __restrict__ flag) {
    const int t = threadIdx.x;
    const int q = t >> 6;              // 0..3
    const int c = t & 63;
    const int n = blockIdx.x * 64 + c;

    float cs = 0.0f;
    #pragma unroll
    for (int i = 0; i < CS_RBLK / 4; ++i)
        cs += partial[(size_t)(q * (CS_RBLK / 4) + i) * N_DIM + n];

    __shared__ float red[4][64];
    __shared__ int w[4];
    if (blockIdx.x == 0) {
        int v = nzp[t] | nzp[t + 256];             // 512 entries
        int any = __any(v != 0 ? 1 : 0) ? 1 : 0;
        if ((t & 63) == 0) w[t >> 6] = any;
    }
    red[q][c] = cs;
    __syncthreads();

    if (blockIdx.x == 0 && t == 0)
        flag[0] = (w[0] | w[1] | w[2] | w[3]);

    if (q == 0) {
        cs = red[0][c] + red[1][c] + red[2][c] + red[3][c];

        const float INFCAP = 100.0f;
        const float EPSV = 1e-4f;

        float p0 = ps[2 * n], p1 = ps[2 * n + 1];
        float p1n = p1 / (p0 + p1);
        float dope = logf(1.0f - p1n) - logf(p1n);

        float m0 = Min[2 * n], m1 = Min[2 * n + 1];
        float m1n = m1 / (m0 + m1);
        float phi = logf(1.0f - m1n) - logf(m1n);

        float prior = dope + phi + cs;
        prior = fminf(fmaxf(prior, -INFCAP), INFCAP);
        float pe = prior + EPSV;

        prior_eps[n] = pe;
        dope_out[n] = dope;
        Tt[n] = tanhf(pe * 0.5f);
        colsum_new[n] = 0.0f;      // pre-zero for main's (rare) atomic path
    }
}

// Main check-node update: ONE WAVE = ONE ROW. grid = K/4 blocks x 256 thr
// (4 independent waves per block). No LDS, no barriers anywhere.
// Per lane: product over 32 int4 chunks -> 6-step butterfly -> P.
// P == 0 (product underflow, the common case at K=4096 factors) -> outputs
// are exactly 0: pure zero-store stream, no colsum contribution.
// Else: recompute t (L1/L2-hot), check_msg, store, atomicAdd column sums.
__global__ __launch_bounds__(256) void main_kernel(const float* __restrict__ Hxs,
                                                   const int* __restrict__ H,
                                                   const int* __restrict__ x,
                                                   const float* __restrict__ prior_eps,
                                                   const float* __restrict__ Tt,
                                                   const int* __restrict__ flag,
                                                   float* __restrict__ out,
                                                   float* __restrict__ colsum_new) {
    const int lane = threadIdx.x & 63;
    const int k = blockIdx.x * 4 + (threadIdx.x >> 6);

    const bool fast = (*flag == 0);
    const int4*   H4  = reinterpret_cast<const int4*>(H + (size_t)k * N_DIM);
    const float4* T4  = reinterpret_cast<const float4*>(Tt);
    const float4* PE4 = reinterpret_cast<const float4*>(prior_eps);
    const float4* HX4 = reinterpret_cast<const float4*>(Hxs + (size_t)k * N_DIM);

    // ---- product over the row (128 elements per lane) ----
    float lp0 = 1.f, lp1 = 1.f, lp2 = 1.f, lp3 = 1.f;
    if (fast) {
        #pragma unroll
        for (int s = 0; s < 32; s += 4) {
            #pragma unroll
            for (int u = 0; u < 4; ++u) {
                const int idx = (s + u) * 64 + lane;
                const int4 hh = H4[idx];
                const float4 tv = T4[idx];
                float f0 = (hh.x && tv.x != 0.f) ? tv.x : 1.f;
                float f1 = (hh.y && tv.y != 0.f) ? tv.y : 1.f;
                float f2 = (hh.z && tv.z != 0.f) ? tv.z : 1.f;
                float f3 = (hh.w && tv.w != 0.f) ? tv.w : 1.f;
                float f = (f0 * f1) * (f2 * f3);
                if (u == 0) lp0 *= f;
                if (u == 1) lp1 *= f;
                if (u == 2) lp2 *= f;
                if (u == 3) lp3 *= f;
            }
        }
    } else {
        #pragma unroll
        for (int s = 0; s < 32; s += 4) {
            #pragma unroll
            for (int u = 0; u < 4; ++u) {
                const int idx = (s + u) * 64 + lane;
                const int4 hh = H4[idx];
                const float4 pe = PE4[idx];
                const float4 hx = HX4[idx];
                float t0 = fast_tanh_half((hh.x ? pe.x : 0.f) - hx.x);
                float t1 = fast_tanh_half((hh.y ? pe.y : 0.f) - hx.y);
                float t2 = fast_tanh_half((hh.z ? pe.z : 0.f) - hx.z);
                float t3 = fast_tanh_half((hh.w ? pe.w : 0.f) - hx.w);
                t0 = (t0 == 0.f) ? 1.f : t0;
                t1 = (t1 == 0.f) ? 1.f : t1;
                t2 = (t2 == 0.f) ? 1.f : t2;
                t3 = (t3 == 0.f) ? 1.f : t3;
                float f = (t0 * t1) * (t2 * t3);
                if (u == 0) lp0 *= f;
                if (u == 1) lp1 *= f;
                if (u == 2) lp2 *= f;
                if (u == 3) lp3 *= f;
            }
        }
    }
    float lp = (lp0 * lp1) * (lp2 * lp3);
    #pragma unroll
    for (int off = 1; off < 64; off <<= 1)
        lp *= __shfl_xor(lp, off);            // all 64 lanes end with full product

    const float sgn = 1.0f - 2.0f * (float)x[k];
    const float P = sgn * lp;

    // ---- outputs ----
    float4* orow = reinterpret_cast<float4*>(out + (size_t)k * N_DIM);
    if (P == 0.0f) {
        // Exact-zero product: every output element is exactly 0
        // (t==0 -> 0; t!=0 -> prod/t = 0 -> 2*atanh(0) = 0). Pure write stream.
        const float4 z = {0.f, 0.f, 0.f, 0.f};
        #pragma unroll
        for (int s = 0; s < 32; ++s)
            orow[s * 64 + lane] = z;
    } else {
        for (int s = 0; s < 32; ++s) {
            const int idx = s * 64 + lane;
            const int4 hh = H4[idx];           // L1/L2-hot (read in product phase)
            float t0, t1, t2, t3;
            if (fast) {
                const float4 tv = T4[idx];
                t0 = (hh.x && tv.x != 0.f) ? tv.x : 0.f;
                t1 = (hh.y && tv.y != 0.f) ? tv.y : 0.f;
                t2 = (hh.z && tv.z != 0.f) ? tv.z : 0.f;
                t3 = (hh.w && tv.w != 0.f) ? tv.w : 0.f;
            } else {
                const float4 pe = PE4[idx];
                const float4 hx = HX4[idx];
                t0 = fast_tanh_half((hh.x ? pe.x : 0.f) - hx.x);
                t1 = fast_tanh_half((hh.y ? pe.y : 0.f) - hx.y);
                t2 = fast_tanh_half((hh.z ? pe.z : 0.f) - hx.z);
                t3 = fast_tanh_half((hh.w ? pe.w : 0.f) - hx.w);
            }
            float4 o;
            o.x = check_msg(t0, P);
            o.y = check_msg(t1, P);
            o.z = check_msg(t2, P);
            o.w = check_msg(t3, P);
            orow[idx] = o;
            const int n0 = idx * 4;
            if (o.x != 0.f) atomicAdd(&colsum_new[n0 + 0], o.x);
            if (o.y != 0.f) atomicAdd(&colsum_new[n0 + 1], o.y);
            if (o.z != 0.f) atomicAdd(&colsum_new[n0 + 2], o.z);
            if (o.w != 0.f) atomicAdd(&colsum_new[n0 + 3], o.w);
        }
    }
}

// Output beliefs. grid = 32 blocks x 256.
__global__ __launch_bounds__(256) void final_kernel(const float* __restrict__ colsum_new,
                                                    const float* __restrict__ dope,
                                                    float* __restrict__ Mout) {
    const int n = blockIdx.x * 256 + threadIdx.x;
    float z = (1.0f - tanhf((colsum_new[n] + dope[n]) * 0.5f)) * 0.5f;
    float2 m; m.x = 1.0f - z; m.y = z;
    reinterpret_cast<float2*>(Mout)[n] = m;
}

extern "C" void kernel_launch(void* const* d_in, const int* in_sizes, int n_in,
                              void* d_out, int out_size, void* d_ws, size_t ws_size,
                              hipStream_t stream) {
    (void)in_sizes; (void)n_in; (void)out_size; (void)ws_size;
    const float* ps  = (const float*)d_in[0];
    const float* Min = (const float*)d_in[1];
    const float* Hxs = (const float*)d_in[2];
    const int*   x   = (const int*)d_in[3];
    const int*   H   = (const int*)d_in[4];

    float* out = (float*)d_out;
    float* Mout = out;                       // N*2 floats
    float* Hxs_new = out + 2 * N_DIM;        // K*N floats

    float* ws = (float*)d_ws;
    float* partial0   = ws;                                  // CS_RBLK*N (2 MB)
    float* prior_eps  = ws + (size_t)CS_RBLK * N_DIM;
    float* dope       = prior_eps + N_DIM;
    float* Tt         = dope + N_DIM;
    float* colsum_new = Tt + N_DIM;
    int*   flag       = (int*)(colsum_new + N_DIM);
    int*   nzp        = flag + 64;                           // 512 ints

    dim3 csgrid(CS_CBLK, CS_RBLK);
    colsum_part_kernel<<<csgrid, 256, 0, stream>>>(Hxs, partial0, nzp);

    prep_kernel<<<N_DIM / 64, 256, 0, stream>>>(ps, Min, partial0, nzp,
                                                prior_eps, dope, Tt, colsum_new, flag);

    main_kernel<<<K_DIM / 4, 256, 0, stream>>>(Hxs, H, x, prior_eps, Tt, flag,
                                               Hxs_new, colsum_new);

    final_kernel<<<N_DIM / 256, 256, 0, stream>>>(colsum_new, dope, Mout);
}

// Round 9
// 78.729 us; speedup vs baseline: 1.5695x; 1.1949x over previous
//
#include <hip/hip_runtime.h>

#define K_DIM 4096
#define N_DIM 8192
#define CS_RBLK 64              // colsum row-blocks (64 rows each)
#define CS_CBLK 8               // colsum col-blocks (1024 cols each)

// clang ext_vector types: accepted by __builtin_nontemporal_load/store
typedef float f32x4 __attribute__((ext_vector_type(4)));
typedef int   i32x4 __attribute__((ext_vector_type(4)));
typedef unsigned int u32x4 __attribute__((ext_vector_type(4)));

// ws float layout (plain stores only, no pre-zeroing needed):
// [0, CS_RBLK*N)  : partial0 (colsum partials, 2 MB)
// then: prior_eps[N], dope[N], Tt[N], Tprod[N], colsum_new[N], flag(int), nzp[512]

__device__ __forceinline__ float fast_tanh_half(float h) {
    // tanh(h/2) = 1 - 2/(e^h + 1)
    float e = __expf(h);
    float r = __builtin_amdgcn_rcpf(e + 1.0f);
    return __builtin_fmaf(-2.0f, r, 1.0f);
}

// out = clip(2*atanh(P/t), -1, 1) for t != 0, else 0.
// 2*atanh(P/t) = ln((t+P)/(t-P))
__device__ __forceinline__ float check_msg(float t, float P) {
    float num = t + P;
    float den = t - P;
    float q = num * __builtin_amdgcn_rcpf(den);
    float m = 0.69314718055994531f * __log2f(q);
    m = fminf(fmaxf(m, -1.0f), 1.0f);
    return (t == 0.0f) ? 0.0f : m;
}

// Partial column sums over [K,N] f32. grid=(CS_CBLK, CS_RBLK), block=256.
// Each thread: 4 consecutive cols x 64 rows. Non-temporal reads (read-once
// stream), plain stores.
__global__ __launch_bounds__(256) void colsum_part_kernel(const float* __restrict__ M,
                                                          float* __restrict__ partial,
                                                          int* __restrict__ nzp) {
    const int c0 = blockIdx.x * 1024 + threadIdx.x * 4;
    const int r0 = blockIdx.y * (K_DIM / CS_RBLK);
    const f32x4* p = reinterpret_cast<const f32x4*>(M + (size_t)r0 * N_DIM + c0);
    float sx = 0.f, sy = 0.f, sz = 0.f, sw = 0.f;
    unsigned int nzbits = 0u;
    #pragma unroll 8
    for (int r = 0; r < K_DIM / CS_RBLK; ++r) {
        f32x4 v = __builtin_nontemporal_load(&p[(size_t)r * (N_DIM / 4)]);
        sx += v.x; sy += v.y; sz += v.z; sw += v.w;
        u32x4 u;
        __builtin_memcpy(&u, &v, 16);
        nzbits |= (u.x | u.y | u.z | u.w);   // false-positive on -0.0 only -> safe general path
    }
    f32x4 s; s.x = sx; s.y = sy; s.z = sz; s.w = sw;
    reinterpret_cast<f32x4*>(partial + (size_t)blockIdx.y * N_DIM)[c0 / 4] = s;

    __shared__ int snz;
    if (threadIdx.x == 0) snz = 0;
    __syncthreads();
    if (__any(nzbits != 0u ? 1 : 0)) {
        if ((threadIdx.x & 63) == 0) atomicOr(&snz, 1);   // LDS atomic only
    }
    __syncthreads();
    if (threadIdx.x == 0)
        nzp[blockIdx.y * gridDim.x + blockIdx.x] = snz;    // plain global store
}

// Fused reduce + per-column prep. grid = 128 blocks x 256 (4-way split per column).
// Also zeros colsum_new (one writer per element) and reduces nzp -> flag (block 0).
__global__ __launch_bounds__(256) void prep_kernel(const float* __restrict__ ps,
                                                   const float* __restrict__ Min,
                                                   const float* __restrict__ partial,
                                                   const int* __restrict__ nzp,
                                                   float* __restrict__ prior_eps,
                                                   float* __restrict__ dope_out,
                                                   float* __restrict__ Tt,
                                                   float* __restrict__ Tprod,
                                                   float* __restrict__ colsum_new,
                                                   int* __restrict__ flag) {
    const int t = threadIdx.x;
    const int q = t >> 6;              // 0..3
    const int c = t & 63;
    const int n = blockIdx.x * 64 + c;

    float cs = 0.0f;
    #pragma unroll
    for (int i = 0; i < CS_RBLK / 4; ++i)
        cs += partial[(size_t)(q * (CS_RBLK / 4) + i) * N_DIM + n];

    __shared__ float red[4][64];
    __shared__ int w[4];
    if (blockIdx.x == 0) {
        int v = nzp[t] | nzp[t + 256];             // 512 entries
        int any = __any(v != 0 ? 1 : 0) ? 1 : 0;
        if ((t & 63) == 0) w[t >> 6] = any;
    }
    red[q][c] = cs;
    __syncthreads();

    if (blockIdx.x == 0 && t == 0)
        flag[0] = (w[0] | w[1] | w[2] | w[3]);

    if (q == 0) {
        cs = red[0][c] + red[1][c] + red[2][c] + red[3][c];

        const float INFCAP = 100.0f;
        const float EPSV = 1e-4f;

        float p0 = ps[2 * n], p1 = ps[2 * n + 1];
        float p1n = p1 / (p0 + p1);
        float dope = logf(1.0f - p1n) - logf(p1n);

        float m0 = Min[2 * n], m1 = Min[2 * n + 1];
        float m1n = m1 / (m0 + m1);
        float phi = logf(1.0f - m1n) - logf(m1n);

        float prior = dope + phi + cs;
        prior = fminf(fmaxf(prior, -INFCAP), INFCAP);
        float pe = prior + EPSV;

        float T = tanhf(pe * 0.5f);
        prior_eps[n] = pe;
        dope_out[n] = dope;
        Tt[n] = T;
        Tprod[n] = (T == 0.0f) ? 1.0f : T;   // product-form table (zero -> identity)
        colsum_new[n] = 0.0f;                // pre-zero for main's (rare) atomic path
    }
}

// Main check-node update: ONE WAVE = HALF A ROW. grid = K/2 blocks x 256 thr
// = 2048 blocks = 8 blocks/CU = 32 waves/CU (full occupancy).
// Wave w (0..3): row = blk*2 + (w>>1), half = w&1. Per lane: 16 int4 chunks.
// Halves combine via 4-float LDS exchange + ONE barrier.
// P == 0 (product underflow, the common case at 4096 factors of |tanh|<1)
// -> outputs are exactly 0: pure nt-zero-store stream, no colsum contribution.
__global__ __launch_bounds__(256) void main_kernel(const float* __restrict__ Hxs,
                                                   const int* __restrict__ H,
                                                   const int* __restrict__ x,
                                                   const float* __restrict__ prior_eps,
                                                   const float* __restrict__ Tt,
                                                   const float* __restrict__ Tprod,
                                                   const int* __restrict__ flag,
                                                   float* __restrict__ out,
                                                   float* __restrict__ colsum_new) {
    const int lane = threadIdx.x & 63;
    const int w = threadIdx.x >> 6;        // 0..3
    const int r = w >> 1;                  // row slot within block
    const int half = w & 1;
    const int k = blockIdx.x * 2 + r;

    const bool fast = (*flag == 0);
    const i32x4*  H4  = reinterpret_cast<const i32x4*>(H + (size_t)k * N_DIM);
    const f32x4*  TP4 = reinterpret_cast<const f32x4*>(Tprod);
    const f32x4*  T4  = reinterpret_cast<const f32x4*>(Tt);
    const f32x4*  PE4 = reinterpret_cast<const f32x4*>(prior_eps);
    const f32x4*  HX4 = reinterpret_cast<const f32x4*>(Hxs + (size_t)k * N_DIM);

    const int base = half * 1024 + lane;   // int4 index of first chunk

    // ---- product over the half-row (64 elements per lane) ----
    float lp0 = 1.f, lp1 = 1.f, lp2 = 1.f, lp3 = 1.f;
    if (fast) {
        #pragma unroll
        for (int s = 0; s < 16; s += 4) {
            #pragma unroll
            for (int u = 0; u < 4; ++u) {
                const int idx = base + (s + u) * 64;
                const i32x4 hh = __builtin_nontemporal_load(&H4[idx]);
                const f32x4 tv = TP4[idx];
                float f0 = hh.x ? tv.x : 1.f;
                float f1 = hh.y ? tv.y : 1.f;
                float f2 = hh.z ? tv.z : 1.f;
                float f3 = hh.w ? tv.w : 1.f;
                float f = (f0 * f1) * (f2 * f3);
                if (u == 0) lp0 *= f;
                if (u == 1) lp1 *= f;
                if (u == 2) lp2 *= f;
                if (u == 3) lp3 *= f;
            }
        }
    } else {
        #pragma unroll
        for (int s = 0; s < 16; s += 4) {
            #pragma unroll
            for (int u = 0; u < 4; ++u) {
                const int idx = base + (s + u) * 64;
                const i32x4 hh = H4[idx];
                const f32x4 pe = PE4[idx];
                const f32x4 hx = HX4[idx];
                float t0 = fast_tanh_half((hh.x ? pe.x : 0.f) - hx.x);
                float t1 = fast_tanh_half((hh.y ? pe.y : 0.f) - hx.y);
                float t2 = fast_tanh_half((hh.z ? pe.z : 0.f) - hx.z);
                float t3 = fast_tanh_half((hh.w ? pe.w : 0.f) - hx.w);
                t0 = (t0 == 0.f) ? 1.f : t0;
                t1 = (t1 == 0.f) ? 1.f : t1;
                t2 = (t2 == 0.f) ? 1.f : t2;
                t3 = (t3 == 0.f) ? 1.f : t3;
                float f = (t0 * t1) * (t2 * t3);
                if (u == 0) lp0 *= f;
                if (u == 1) lp1 *= f;
                if (u == 2) lp2 *= f;
                if (u == 3) lp3 *= f;
            }
        }
    }
    float lp = (lp0 * lp1) * (lp2 * lp3);
    #pragma unroll
    for (int off = 1; off < 64; off <<= 1)
        lp *= __shfl_xor(lp, off);

    __shared__ float sh[4];
    if (lane == 0) sh[w] = lp;
    __syncthreads();                        // the only barrier
    const float rowprod = sh[w] * sh[w ^ 1];

    const float sgn = 1.0f - 2.0f * (float)x[k];
    const float P = sgn * rowprod;

    // ---- outputs ----
    f32x4* orow = reinterpret_cast<f32x4*>(out + (size_t)k * N_DIM);
    if (P == 0.0f) {
        // Exact-zero product: every output element is exactly 0
        // (t==0 -> 0; t!=0 -> 2*atanh(0/..) = 0). Pure nt write stream.
        const f32x4 z = {0.f, 0.f, 0.f, 0.f};
        #pragma unroll
        for (int s = 0; s < 16; ++s)
            __builtin_nontemporal_store(z, &orow[base + s * 64]);
    } else {
        for (int s = 0; s < 16; ++s) {
            const int idx = base + s * 64;
            const i32x4 hh = H4[idx];
            float t0, t1, t2, t3;
            if (fast) {
                const f32x4 tv = T4[idx];
                t0 = hh.x ? tv.x : 0.f;
                t1 = hh.y ? tv.y : 0.f;
                t2 = hh.z ? tv.z : 0.f;
                t3 = hh.w ? tv.w : 0.f;
            } else {
                const f32x4 pe = PE4[idx];
                const f32x4 hx = HX4[idx];
                t0 = fast_tanh_half((hh.x ? pe.x : 0.f) - hx.x);
                t1 = fast_tanh_half((hh.y ? pe.y : 0.f) - hx.y);
                t2 = fast_tanh_half((hh.z ? pe.z : 0.f) - hx.z);
                t3 = fast_tanh_half((hh.w ? pe.w : 0.f) - hx.w);
            }
            f32x4 o;
            o.x = check_msg(t0, P);
            o.y = check_msg(t1, P);
            o.z = check_msg(t2, P);
            o.w = check_msg(t3, P);
            __builtin_nontemporal_store(o, &orow[idx]);
            const int n0 = idx * 4;
            if (o.x != 0.f) atomicAdd(&colsum_new[n0 + 0], o.x);
            if (o.y != 0.f) atomicAdd(&colsum_new[n0 + 1], o.y);
            if (o.z != 0.f) atomicAdd(&colsum_new[n0 + 2], o.z);
            if (o.w != 0.f) atomicAdd(&colsum_new[n0 + 3], o.w);
        }
    }
}

// Output beliefs. grid = 32 blocks x 256.
__global__ __launch_bounds__(256) void final_kernel(const float* __restrict__ colsum_new,
                                                    const float* __restrict__ dope,
                                                    float* __restrict__ Mout) {
    const int n = blockIdx.x * 256 + threadIdx.x;
    float z = (1.0f - tanhf((colsum_new[n] + dope[n]) * 0.5f)) * 0.5f;
    float2 m; m.x = 1.0f - z; m.y = z;
    reinterpret_cast<float2*>(Mout)[n] = m;
}

extern "C" void kernel_launch(void* const* d_in, const int* in_sizes, int n_in,
                              void* d_out, int out_size, void* d_ws, size_t ws_size,
                              hipStream_t stream) {
    (void)in_sizes; (void)n_in; (void)out_size; (void)ws_size;
    const float* ps  = (const float*)d_in[0];
    const float* Min = (const float*)d_in[1];
    const float* Hxs = (const float*)d_in[2];
    const int*   x   = (const int*)d_in[3];
    const int*   H   = (const int*)d_in[4];

    float* out = (float*)d_out;
    float* Mout = out;                       // N*2 floats
    float* Hxs_new = out + 2 * N_DIM;        // K*N floats

    float* ws = (float*)d_ws;
    float* partial0   = ws;                                  // CS_RBLK*N (2 MB)
    float* prior_eps  = ws + (size_t)CS_RBLK * N_DIM;
    float* dope       = prior_eps + N_DIM;
    float* Tt         = dope + N_DIM;
    float* Tprod      = Tt + N_DIM;
    float* colsum_new = Tprod + N_DIM;
    int*   flag       = (int*)(colsum_new + N_DIM);
    int*   nzp        = flag + 64;                           // 512 ints

    dim3 csgrid(CS_CBLK, CS_RBLK);
    colsum_part_kernel<<<csgrid, 256, 0, stream>>>(Hxs, partial0, nzp);

    prep_kernel<<<N_DIM / 64, 256, 0, stream>>>(ps, Min, partial0, nzp,
                                                prior_eps, dope, Tt, Tprod,
                                                colsum_new, flag);

    main_kernel<<<K_DIM / 2, 256, 0, stream>>>(Hxs, H, x, prior_eps, Tt, Tprod,
                                               flag, Hxs_new, colsum_new);

    final_kernel<<<N_DIM / 256, 256, 0, stream>>>(colsum_new, dope, Mout);
}

// Round 10
// 58.654 us; speedup vs baseline: 2.1067x; 1.3423x over previous
//
#include <hip/hip_runtime.h>

#define K_DIM 4096
#define N_DIM 8192
#define CS_RBLK 64              // colsum row-blocks (64 rows each)
#define CS_CBLK 8               // colsum col-blocks (1024 cols each)

// clang ext_vector types: accepted by __builtin_nontemporal_load/store
typedef float f32x4 __attribute__((ext_vector_type(4)));
typedef int   i32x4 __attribute__((ext_vector_type(4)));
typedef unsigned int u32x4 __attribute__((ext_vector_type(4)));

// ws float layout (plain stores only, no pre-zeroing needed):
// [0, CS_RBLK*N)  : partial0 (colsum partials, 2 MB)
// then: prior_eps[N], dope[N], Tt[N], Tprod[N], colsum_new[N], flag(int), nzp[512]

__device__ __forceinline__ float fast_tanh_half(float h) {
    // tanh(h/2) = 1 - 2/(e^h + 1)
    float e = __expf(h);
    float r = __builtin_amdgcn_rcpf(e + 1.0f);
    return __builtin_fmaf(-2.0f, r, 1.0f);
}

// out = clip(2*atanh(P/t), -1, 1) for t != 0, else 0.
// 2*atanh(P/t) = ln((t+P)/(t-P))
__device__ __forceinline__ float check_msg(float t, float P) {
    float num = t + P;
    float den = t - P;
    float q = num * __builtin_amdgcn_rcpf(den);
    float m = 0.69314718055994531f * __log2f(q);
    m = fminf(fmaxf(m, -1.0f), 1.0f);
    return (t == 0.0f) ? 0.0f : m;
}

// Partial column sums over [K,N] f32. grid=(CS_CBLK, CS_RBLK), block=256.
// Each thread: 4 consecutive cols x 64 rows. Non-temporal reads, plain stores.
__global__ __launch_bounds__(256) void colsum_part_kernel(const float* __restrict__ M,
                                                          float* __restrict__ partial,
                                                          int* __restrict__ nzp) {
    const int c0 = blockIdx.x * 1024 + threadIdx.x * 4;
    const int r0 = blockIdx.y * (K_DIM / CS_RBLK);
    const f32x4* p = reinterpret_cast<const f32x4*>(M + (size_t)r0 * N_DIM + c0);
    float sx = 0.f, sy = 0.f, sz = 0.f, sw = 0.f;
    unsigned int nzbits = 0u;
    #pragma unroll 8
    for (int r = 0; r < K_DIM / CS_RBLK; ++r) {
        f32x4 v = __builtin_nontemporal_load(&p[(size_t)r * (N_DIM / 4)]);
        sx += v.x; sy += v.y; sz += v.z; sw += v.w;
        u32x4 u;
        __builtin_memcpy(&u, &v, 16);
        nzbits |= (u.x | u.y | u.z | u.w);   // false-positive on -0.0 only -> safe general path
    }
    f32x4 s; s.x = sx; s.y = sy; s.z = sz; s.w = sw;
    reinterpret_cast<f32x4*>(partial + (size_t)blockIdx.y * N_DIM)[c0 / 4] = s;

    __shared__ int snz;
    if (threadIdx.x == 0) snz = 0;
    __syncthreads();
    if (__any(nzbits != 0u ? 1 : 0)) {
        if ((threadIdx.x & 63) == 0) atomicOr(&snz, 1);   // LDS atomic only
    }
    __syncthreads();
    if (threadIdx.x == 0)
        nzp[blockIdx.y * gridDim.x + blockIdx.x] = snz;    // plain global store
}

// Fused reduce + per-column prep. grid = 128 blocks x 256 (4-way split per column).
// Also zeros colsum_new (one writer per element) and reduces nzp -> flag (block 0).
__global__ __launch_bounds__(256) void prep_kernel(const float* __restrict__ ps,
                                                   const float* __restrict__ Min,
                                                   const float* __restrict__ partial,
                                                   const int* __restrict__ nzp,
                                                   float* __restrict__ prior_eps,
                                                   float* __restrict__ dope_out,
                                                   float* __restrict__ Tt,
                                                   float* __restrict__ Tprod,
                                                   float* __restrict__ colsum_new,
                                                   int* __restrict__ flag) {
    const int t = threadIdx.x;
    const int q = t >> 6;              // 0..3
    const int c = t & 63;
    const int n = blockIdx.x * 64 + c;

    float cs = 0.0f;
    #pragma unroll
    for (int i = 0; i < CS_RBLK / 4; ++i)
        cs += partial[(size_t)(q * (CS_RBLK / 4) + i) * N_DIM + n];

    __shared__ float red[4][64];
    __shared__ int w[4];
    if (blockIdx.x == 0) {
        int v = nzp[t] | nzp[t + 256];             // 512 entries
        int any = __any(v != 0 ? 1 : 0) ? 1 : 0;
        if ((t & 63) == 0) w[t >> 6] = any;
    }
    red[q][c] = cs;
    __syncthreads();

    if (blockIdx.x == 0 && t == 0)
        flag[0] = (w[0] | w[1] | w[2] | w[3]);

    if (q == 0) {
        cs = red[0][c] + red[1][c] + red[2][c] + red[3][c];

        const float INFCAP = 100.0f;
        const float EPSV = 1e-4f;

        float p0 = ps[2 * n], p1 = ps[2 * n + 1];
        float p1n = p1 / (p0 + p1);
        float dope = logf(1.0f - p1n) - logf(p1n);

        float m0 = Min[2 * n], m1 = Min[2 * n + 1];
        float m1n = m1 / (m0 + m1);
        float phi = logf(1.0f - m1n) - logf(m1n);

        float prior = dope + phi + cs;
        prior = fminf(fmaxf(prior, -INFCAP), INFCAP);
        float pe = prior + EPSV;

        float T = tanhf(pe * 0.5f);
        prior_eps[n] = pe;
        dope_out[n] = dope;
        Tt[n] = T;
        Tprod[n] = (T == 0.0f) ? 1.0f : T;   // product-form table (zero -> identity)
        colsum_new[n] = 0.0f;                // pre-zero for main's (rare) atomic path
    }
}

// Main check-node update: ONE WAVE = ONE ROW, no LDS, no barriers.
// grid = K/4 blocks x 256 thr (4 independent waves/block).
// KEY: all factors |t| <= 1, so the row-product magnitude is monotonically
// non-increasing. Read only the FIRST 4 of 32 chunks (1024 columns),
// butterfly; if that prefix product is exactly 0, the full product is 0 and
// every output of the row is exactly 0 -> stream nt zero-stores, skip the
// remaining 28/32 of H. Fallback reads the rest and does the full
// leave-one-out epilogue (bit-identical to the reference semantics).
__global__ __launch_bounds__(256) void main_kernel(const float* __restrict__ Hxs,
                                                   const int* __restrict__ H,
                                                   const int* __restrict__ x,
                                                   const float* __restrict__ prior_eps,
                                                   const float* __restrict__ Tt,
                                                   const float* __restrict__ Tprod,
                                                   const int* __restrict__ flag,
                                                   float* __restrict__ out,
                                                   float* __restrict__ colsum_new) {
    const int lane = threadIdx.x & 63;
    const int k = blockIdx.x * 4 + (threadIdx.x >> 6);

    const bool fast = (*flag == 0);
    const i32x4* H4  = reinterpret_cast<const i32x4*>(H + (size_t)k * N_DIM);
    const f32x4* TP4 = reinterpret_cast<const f32x4*>(Tprod);
    const f32x4* T4  = reinterpret_cast<const f32x4*>(Tt);
    const f32x4* PE4 = reinterpret_cast<const f32x4*>(prior_eps);
    const f32x4* HX4 = reinterpret_cast<const f32x4*>(Hxs + (size_t)k * N_DIM);

    // ---- prefix product: first 4 chunks (1024 columns; Tprod[0:1024] is
    //      shared by all rows -> L2-resident) ----
    float lp0 = 1.f, lp1 = 1.f, lp2 = 1.f, lp3 = 1.f;
    #pragma unroll
    for (int u = 0; u < 4; ++u) {
        const int idx = u * 64 + lane;
        const i32x4 hh = H4[idx];
        float f;
        if (fast) {
            const f32x4 tv = TP4[idx];
            float f0 = hh.x ? tv.x : 1.f;
            float f1 = hh.y ? tv.y : 1.f;
            float f2 = hh.z ? tv.z : 1.f;
            float f3 = hh.w ? tv.w : 1.f;
            f = (f0 * f1) * (f2 * f3);
        } else {
            const f32x4 pe = PE4[idx];
            const f32x4 hx = HX4[idx];
            float t0 = fast_tanh_half((hh.x ? pe.x : 0.f) - hx.x);
            float t1 = fast_tanh_half((hh.y ? pe.y : 0.f) - hx.y);
            float t2 = fast_tanh_half((hh.z ? pe.z : 0.f) - hx.z);
            float t3 = fast_tanh_half((hh.w ? pe.w : 0.f) - hx.w);
            t0 = (t0 == 0.f) ? 1.f : t0;
            t1 = (t1 == 0.f) ? 1.f : t1;
            t2 = (t2 == 0.f) ? 1.f : t2;
            t3 = (t3 == 0.f) ? 1.f : t3;
            f = (t0 * t1) * (t2 * t3);
        }
        if (u == 0) lp0 *= f;
        if (u == 1) lp1 *= f;
        if (u == 2) lp2 *= f;
        if (u == 3) lp3 *= f;
    }
    float pp = (lp0 * lp1) * (lp2 * lp3);
    #pragma unroll
    for (int off = 1; off < 64; off <<= 1)
        pp *= __shfl_xor(pp, off);          // prefix product, all lanes

    f32x4* orow = reinterpret_cast<f32x4*>(out + (size_t)k * N_DIM);

    if (pp == 0.0f) {
        // Full product is exactly 0 -> every output exactly 0.
        const f32x4 z = {0.f, 0.f, 0.f, 0.f};
        #pragma unroll
        for (int s = 0; s < 32; ++s)
            __builtin_nontemporal_store(z, &orow[s * 64 + lane]);
        return;
    }

    // ---- rare path: finish the product over chunks 4..31 ----
    float mp0 = 1.f, mp1 = 1.f, mp2 = 1.f, mp3 = 1.f;
    for (int s = 4; s < 32; s += 4) {
        #pragma unroll
        for (int u = 0; u < 4; ++u) {
            const int idx = (s + u) * 64 + lane;
            const i32x4 hh = H4[idx];
            float f;
            if (fast) {
                const f32x4 tv = TP4[idx];
                float f0 = hh.x ? tv.x : 1.f;
                float f1 = hh.y ? tv.y : 1.f;
                float f2 = hh.z ? tv.z : 1.f;
                float f3 = hh.w ? tv.w : 1.f;
                f = (f0 * f1) * (f2 * f3);
            } else {
                const f32x4 pe = PE4[idx];
                const f32x4 hx = HX4[idx];
                float t0 = fast_tanh_half((hh.x ? pe.x : 0.f) - hx.x);
                float t1 = fast_tanh_half((hh.y ? pe.y : 0.f) - hx.y);
                float t2 = fast_tanh_half((hh.z ? pe.z : 0.f) - hx.z);
                float t3 = fast_tanh_half((hh.w ? pe.w : 0.f) - hx.w);
                t0 = (t0 == 0.f) ? 1.f : t0;
                t1 = (t1 == 0.f) ? 1.f : t1;
                t2 = (t2 == 0.f) ? 1.f : t2;
                t3 = (t3 == 0.f) ? 1.f : t3;
                f = (t0 * t1) * (t2 * t3);
            }
            if (u == 0) mp0 *= f;
            if (u == 1) mp1 *= f;
            if (u == 2) mp2 *= f;
            if (u == 3) mp3 *= f;
        }
    }
    float rest = (mp0 * mp1) * (mp2 * mp3);
    #pragma unroll
    for (int off = 1; off < 64; off <<= 1)
        rest *= __shfl_xor(rest, off);

    const float sgn = 1.0f - 2.0f * (float)x[k];
    const float P = sgn * pp * rest;

    for (int s = 0; s < 32; ++s) {
        const int idx = s * 64 + lane;
        const i32x4 hh = H4[idx];
        float t0, t1, t2, t3;
        if (fast) {
            const f32x4 tv = T4[idx];
            t0 = hh.x ? tv.x : 0.f;
            t1 = hh.y ? tv.y : 0.f;
            t2 = hh.z ? tv.z : 0.f;
            t3 = hh.w ? tv.w : 0.f;
        } else {
            const f32x4 pe = PE4[idx];
            const f32x4 hx = HX4[idx];
            t0 = fast_tanh_half((hh.x ? pe.x : 0.f) - hx.x);
            t1 = fast_tanh_half((hh.y ? pe.y : 0.f) - hx.y);
            t2 = fast_tanh_half((hh.z ? pe.z : 0.f) - hx.z);
            t3 = fast_tanh_half((hh.w ? pe.w : 0.f) - hx.w);
        }
        f32x4 o;
        o.x = check_msg(t0, P);
        o.y = check_msg(t1, P);
        o.z = check_msg(t2, P);
        o.w = check_msg(t3, P);
        __builtin_nontemporal_store(o, &orow[idx]);
        const int n0 = idx * 4;
        if (o.x != 0.f) atomicAdd(&colsum_new[n0 + 0], o.x);
        if (o.y != 0.f) atomicAdd(&colsum_new[n0 + 1], o.y);
        if (o.z != 0.f) atomicAdd(&colsum_new[n0 + 2], o.z);
        if (o.w != 0.f) atomicAdd(&colsum_new[n0 + 3], o.w);
    }
}

// Output beliefs. grid = 32 blocks x 256.
__global__ __launch_bounds__(256) void final_kernel(const float* __restrict__ colsum_new,
                                                    const float* __restrict__ dope,
                                                    float* __restrict__ Mout) {
    const int n = blockIdx.x * 256 + threadIdx.x;
    float z = (1.0f - tanhf((colsum_new[n] + dope[n]) * 0.5f)) * 0.5f;
    float2 m; m.x = 1.0f - z; m.y = z;
    reinterpret_cast<float2*>(Mout)[n] = m;
}

extern "C" void kernel_launch(void* const* d_in, const int* in_sizes, int n_in,
                              void* d_out, int out_size, void* d_ws, size_t ws_size,
                              hipStream_t stream) {
    (void)in_sizes; (void)n_in; (void)out_size; (void)ws_size;
    const float* ps  = (const float*)d_in[0];
    const float* Min = (const float*)d_in[1];
    const float* Hxs = (const float*)d_in[2];
    const int*   x   = (const int*)d_in[3];
    const int*   H   = (const int*)d_in[4];

    float* out = (float*)d_out;
    float* Mout = out;                       // N*2 floats
    float* Hxs_new = out + 2 * N_DIM;        // K*N floats

    float* ws = (float*)d_ws;
    float* partial0   = ws;                                  // CS_RBLK*N (2 MB)
    float* prior_eps  = ws + (size_t)CS_RBLK * N_DIM;
    float* dope       = prior_eps + N_DIM;
    float* Tt         = dope + N_DIM;
    float* Tprod      = Tt + N_DIM;
    float* colsum_new = Tprod + N_DIM;
    int*   flag       = (int*)(colsum_new + N_DIM);
    int*   nzp        = flag + 64;                           // 512 ints

    dim3 csgrid(CS_CBLK, CS_RBLK);
    colsum_part_kernel<<<csgrid, 256, 0, stream>>>(Hxs, partial0, nzp);

    prep_kernel<<<N_DIM / 64, 256, 0, stream>>>(ps, Min, partial0, nzp,
                                                prior_eps, dope, Tt, Tprod,
                                                colsum_new, flag);

    main_kernel<<<K_DIM / 4, 256, 0, stream>>>(Hxs, H, x, prior_eps, Tt, Tprod,
                                               flag, Hxs_new, colsum_new);

    final_kernel<<<N_DIM / 256, 256, 0, stream>>>(colsum_new, dope, Mout);
}